// Round 1
// baseline (894.010 us; speedup 1.0000x reference)
//
#include <hip/hip_runtime.h>
#include <cstdint>

#define DIN 4096
#define DOUT 4096
#define QMAXF 127.0f

typedef int v4i __attribute__((ext_vector_type(4)));
typedef unsigned int u32;

__device__ __forceinline__ void async16(const void* g, void* l) {
  __builtin_amdgcn_global_load_lds((const __attribute__((address_space(1))) u32*)g,
                                   (__attribute__((address_space(3))) u32*)l,
                                   16, 0, 0);
}

__device__ __forceinline__ int clamp_q(float v) {
  int i = (int)rintf(v);           // v_rndne: round half to even, matches np.round
  return i < -128 ? -128 : (i > 127 ? 127 : i);
}

// --- Kernel 1: ternary f32 weights -> int8 (w values are exactly -1/0/1) ---
__global__ __launch_bounds__(256) void wconvert_kernel(const float* __restrict__ w,
                                                       int8_t* __restrict__ wq) {
  int t = blockIdx.x * 256 + threadIdx.x;
  float4 v = ((const float4*)w)[t];
  int b0 = ((int)v.x) & 255, b1 = ((int)v.y) & 255;
  int b2 = ((int)v.z) & 255, b3 = ((int)v.w) & 255;
  ((int*)wq)[t] = b0 | (b1 << 8) | (b2 << 16) | (b3 << 24);
}

// --- Kernel 2: RMSNorm + per-token absmax int8 quant ---
__global__ __launch_bounds__(256) void rmsnorm_quant_kernel(
    const float* __restrict__ x, const float* __restrict__ gamma,
    const float* __restrict__ scale_w_ptr, int8_t* __restrict__ xq,
    float* __restrict__ inv_scale) {
  const int token = blockIdx.x;
  const float* xr = x + (size_t)token * DIN;
  const int t = threadIdx.x;

  float4 xv[4], gv[4];
  float ss = 0.f, amax = 0.f;
#pragma unroll
  for (int i = 0; i < 4; ++i) {
    const int idx = (i * 256 + t) * 4;
    xv[i] = *(const float4*)(xr + idx);
    gv[i] = *(const float4*)(gamma + idx);
    ss += xv[i].x * xv[i].x + xv[i].y * xv[i].y + xv[i].z * xv[i].z + xv[i].w * xv[i].w;
    amax = fmaxf(amax, fabsf(xv[i].x * gv[i].x));
    amax = fmaxf(amax, fabsf(xv[i].y * gv[i].y));
    amax = fmaxf(amax, fabsf(xv[i].z * gv[i].z));
    amax = fmaxf(amax, fabsf(xv[i].w * gv[i].w));
  }
#pragma unroll
  for (int o = 32; o > 0; o >>= 1) {
    ss += __shfl_down(ss, o);
    amax = fmaxf(amax, __shfl_down(amax, o));
  }
  __shared__ float s_ss[4], s_am[4];
  const int wave = t >> 6, lane = t & 63;
  if (lane == 0) { s_ss[wave] = ss; s_am[wave] = amax; }
  __syncthreads();
  const float tot = s_ss[0] + s_ss[1] + s_ss[2] + s_ss[3];
  const float mx = fmaxf(fmaxf(s_am[0], s_am[1]), fmaxf(s_am[2], s_am[3]));
  const float rstd = rsqrtf(tot * (1.0f / DIN) + 1e-5f);
  const float absmax = fmaxf(mx * rstd, 1e-5f);
  const float qscale = rstd * (QMAXF / absmax);
  if (t == 0) inv_scale[token] = absmax / (QMAXF * scale_w_ptr[0]);

  int* qr = (int*)(xq + (size_t)token * DIN);
#pragma unroll
  for (int i = 0; i < 4; ++i) {
    const int idx4 = i * 256 + t;
    int b0 = clamp_q(xv[i].x * gv[i].x * qscale) & 255;
    int b1 = clamp_q(xv[i].y * gv[i].y * qscale) & 255;
    int b2 = clamp_q(xv[i].z * gv[i].z * qscale) & 255;
    int b3 = clamp_q(xv[i].w * gv[i].w * qscale) & 255;
    qr[idx4] = b0 | (b1 << 8) | (b2 << 16) | (b3 << 24);
  }
}

// --- Kernel 3: int8 GEMM, 128x128 tile, BK=128, swizzled LDS,
//     2-phase double-buffered prefetch (T3 minimum recipe).
// LDS layout: logical 16B chunk (row, cb) stored at phys chunk (cb+row)&7
// within the row. Staging (global_load_lds, dest = base + lane*16) permutes
// the GLOBAL source column instead: thread handling phys chunk p reads
// logical cb = (p - row) & 7. Fragment reads: every 8-lane group covers all
// 32 banks -> zero conflicts (SQ_LDS_BANK_CONFLICT measured 0).
// K-loop: prefetch tile kt+1 into buf^1 via global_load_lds, THEN compute
// tile kt from buf; single __syncthreads() per K-tile both drains vmcnt(0)
// (prefetched tile landed) and fences lgkm (all waves done reading buf
// before it is overwritten next iteration).
#define BM 128
#define BN 128
#define BK 128

__global__ __launch_bounds__(256) void gemm_i8_kernel(
    const int8_t* __restrict__ xq, const int8_t* __restrict__ wq,
    const float* __restrict__ inv_scale, const float* __restrict__ bias,
    float* __restrict__ out) {
  __shared__ int8_t As[2][BM * BK];   // 2 x 16 KB
  __shared__ int8_t Bs[2][BN * BK];   // 2 x 16 KB

  const int t = threadIdx.x;
  const int wave = t >> 6;
  const int lane = t & 63;
  const int m0 = blockIdx.y * BM;
  const int n0 = blockIdx.x * BN;

  // staging: thread t handles phys chunks p = i*256 + t (i=0..3) of each tile
  int srow[4], scol[4];
#pragma unroll
  for (int i = 0; i < 4; ++i) {
    const int p = i * 256 + t;
    srow[i] = p >> 3;                    // tile row
    scol[i] = ((p - (p >> 3)) & 7) * 16; // logical 16B-chunk byte offset in row
  }

  const int8_t* Ag = xq + (size_t)m0 * DIN;
  const int8_t* Bg = wq + (size_t)n0 * DIN;

  v4i acc[4][4];
#pragma unroll
  for (int mi = 0; mi < 4; ++mi)
#pragma unroll
    for (int ni = 0; ni < 4; ++ni) acc[mi][ni] = (v4i){0, 0, 0, 0};

  const int wm = (wave >> 1) * 64;   // 2x2 wave grid, 64x64 out per wave
  const int wn = (wave & 1) * 64;
  const int fr = lane & 15;          // fragment row (m or n)
  const int q = lane >> 4;           // k quarter

  // fragment LDS byte offsets (swizzled)
  int offA[2][4], offB[2][4];
#pragma unroll
  for (int s = 0; s < 2; ++s)
#pragma unroll
    for (int j = 0; j < 4; ++j) {
      const int sw = ((s * 4 + q + fr) & 7) * 16;
      offA[s][j] = (wm + j * 16 + fr) * BK + sw;
      offB[s][j] = (wn + j * 16 + fr) * BK + sw;
    }

  auto mma_tile = [&](const int8_t* Ab, const int8_t* Bb) {
#pragma unroll
    for (int s = 0; s < 2; ++s) {
      v4i a[4], b[4];
#pragma unroll
      for (int j = 0; j < 4; ++j) a[j] = *(const v4i*)(Ab + offA[s][j]);
#pragma unroll
      for (int j = 0; j < 4; ++j) b[j] = *(const v4i*)(Bb + offB[s][j]);
#pragma unroll
      for (int mi = 0; mi < 4; ++mi)
#pragma unroll
        for (int ni = 0; ni < 4; ++ni)
          acc[mi][ni] = __builtin_amdgcn_mfma_i32_16x16x64_i8(a[mi], b[ni], acc[mi][ni], 0, 0, 0);
    }
  };

  // prologue: stage tile 0 into buffer 0
#pragma unroll
  for (int i = 0; i < 4; ++i)
    async16(Ag + (size_t)srow[i] * DIN + scol[i], &As[0][i * 4096 + t * 16]);
#pragma unroll
  for (int i = 0; i < 4; ++i)
    async16(Bg + (size_t)srow[i] * DIN + scol[i], &Bs[0][i * 4096 + t * 16]);
  __syncthreads();   // vmcnt(0): tile 0 resident

  int cur = 0;
  const int NT = DIN / BK;   // 32
  for (int kt = 0; kt < NT - 1; ++kt) {
    const int kn = (kt + 1) * BK;
    // issue next-tile loads first: they fly during the MFMAs below
#pragma unroll
    for (int i = 0; i < 4; ++i)
      async16(Ag + (size_t)srow[i] * DIN + kn + scol[i], &As[cur ^ 1][i * 4096 + t * 16]);
#pragma unroll
    for (int i = 0; i < 4; ++i)
      async16(Bg + (size_t)srow[i] * DIN + kn + scol[i], &Bs[cur ^ 1][i * 4096 + t * 16]);

    mma_tile(As[cur], Bs[cur]);

    __syncthreads();   // drains vmcnt(0)+lgkmcnt(0); next tile ready, cur free
    cur ^= 1;
  }
  // last tile: no prefetch
  mma_tile(As[cur], Bs[cur]);

  // epilogue: C/D layout col = lane&15, row = (lane>>4)*4 + reg
  const int col = lane & 15;
  const int rb = (lane >> 4) * 4;
#pragma unroll
  for (int mi = 0; mi < 4; ++mi) {
    float sc[4];
#pragma unroll
    for (int r = 0; r < 4; ++r) sc[r] = inv_scale[m0 + wm + mi * 16 + rb + r];
#pragma unroll
    for (int ni = 0; ni < 4; ++ni) {
      const int gc = n0 + wn + ni * 16 + col;
      const float bb = bias[gc];
#pragma unroll
      for (int r = 0; r < 4; ++r) {
        const int gr = m0 + wm + mi * 16 + rb + r;
        out[(size_t)gr * DOUT + gc] = (float)acc[mi][ni][r] * sc[r] + bb;
      }
    }
  }
}

extern "C" void kernel_launch(void* const* d_in, const int* in_sizes, int n_in,
                              void* d_out, int out_size, void* d_ws, size_t ws_size,
                              hipStream_t stream) {
  const float* x       = (const float*)d_in[0];
  const float* w       = (const float*)d_in[1];
  const float* scale_w = (const float*)d_in[2];
  const float* gamma   = (const float*)d_in[3];
  const float* bias    = (const float*)d_in[4];
  float* out = (float*)d_out;
  const int M = in_sizes[0] / DIN;   // 16384

  // workspace layout: wq (16 MB) | xq (64 MB) | inv_scale (64 KB)
  int8_t* wq = (int8_t*)d_ws;
  int8_t* xq = wq + (size_t)DOUT * DIN;
  float* inv_scale = (float*)(xq + (size_t)M * DIN);

  hipLaunchKernelGGL(wconvert_kernel, dim3((DOUT * DIN) / (256 * 4)), dim3(256), 0, stream,
                     w, wq);
  hipLaunchKernelGGL(rmsnorm_quant_kernel, dim3(M), dim3(256), 0, stream,
                     x, gamma, scale_w, xq, inv_scale);
  hipLaunchKernelGGL(gemm_i8_kernel, dim3(DOUT / BN, M / BM), dim3(256), 0, stream,
                     xq, wq, inv_scale, bias, out);
}

// Round 2
// 788.640 us; speedup vs baseline: 1.1336x; 1.1336x over previous
//
#include <hip/hip_runtime.h>
#include <cstdint>

#define DIN 4096
#define DOUT 4096
#define QMAXF 127.0f

typedef int v4i __attribute__((ext_vector_type(4)));
typedef unsigned int u32;

__device__ __forceinline__ void async16(const void* g, void* l) {
  __builtin_amdgcn_global_load_lds((const __attribute__((address_space(1))) u32*)g,
                                   (__attribute__((address_space(3))) u32*)l,
                                   16, 0, 0);
}

__device__ __forceinline__ int clamp_q(float v) {
  int i = (int)rintf(v);           // v_rndne: round half to even, matches np.round
  return i < -128 ? -128 : (i > 127 ? 127 : i);
}

// --- Kernel 1: ternary f32 weights -> int8 (w values are exactly -1/0/1) ---
__global__ __launch_bounds__(256) void wconvert_kernel(const float* __restrict__ w,
                                                       int8_t* __restrict__ wq) {
  int t = blockIdx.x * 256 + threadIdx.x;
  float4 v = ((const float4*)w)[t];
  int b0 = ((int)v.x) & 255, b1 = ((int)v.y) & 255;
  int b2 = ((int)v.z) & 255, b3 = ((int)v.w) & 255;
  ((int*)wq)[t] = b0 | (b1 << 8) | (b2 << 16) | (b3 << 24);
}

// --- Kernel 2: RMSNorm + per-token absmax int8 quant ---
__global__ __launch_bounds__(256) void rmsnorm_quant_kernel(
    const float* __restrict__ x, const float* __restrict__ gamma,
    const float* __restrict__ scale_w_ptr, int8_t* __restrict__ xq,
    float* __restrict__ inv_scale) {
  const int token = blockIdx.x;
  const float* xr = x + (size_t)token * DIN;
  const int t = threadIdx.x;

  float4 xv[4], gv[4];
  float ss = 0.f, amax = 0.f;
#pragma unroll
  for (int i = 0; i < 4; ++i) {
    const int idx = (i * 256 + t) * 4;
    xv[i] = *(const float4*)(xr + idx);
    gv[i] = *(const float4*)(gamma + idx);
    ss += xv[i].x * xv[i].x + xv[i].y * xv[i].y + xv[i].z * xv[i].z + xv[i].w * xv[i].w;
    amax = fmaxf(amax, fabsf(xv[i].x * gv[i].x));
    amax = fmaxf(amax, fabsf(xv[i].y * gv[i].y));
    amax = fmaxf(amax, fabsf(xv[i].z * gv[i].z));
    amax = fmaxf(amax, fabsf(xv[i].w * gv[i].w));
  }
#pragma unroll
  for (int o = 32; o > 0; o >>= 1) {
    ss += __shfl_down(ss, o);
    amax = fmaxf(amax, __shfl_down(amax, o));
  }
  __shared__ float s_ss[4], s_am[4];
  const int wave = t >> 6, lane = t & 63;
  if (lane == 0) { s_ss[wave] = ss; s_am[wave] = amax; }
  __syncthreads();
  const float tot = s_ss[0] + s_ss[1] + s_ss[2] + s_ss[3];
  const float mx = fmaxf(fmaxf(s_am[0], s_am[1]), fmaxf(s_am[2], s_am[3]));
  const float rstd = rsqrtf(tot * (1.0f / DIN) + 1e-5f);
  const float absmax = fmaxf(mx * rstd, 1e-5f);
  const float qscale = rstd * (QMAXF / absmax);
  if (t == 0) inv_scale[token] = absmax / (QMAXF * scale_w_ptr[0]);

  int* qr = (int*)(xq + (size_t)token * DIN);
#pragma unroll
  for (int i = 0; i < 4; ++i) {
    const int idx4 = i * 256 + t;
    int b0 = clamp_q(xv[i].x * gv[i].x * qscale) & 255;
    int b1 = clamp_q(xv[i].y * gv[i].y * qscale) & 255;
    int b2 = clamp_q(xv[i].z * gv[i].z * qscale) & 255;
    int b3 = clamp_q(xv[i].w * gv[i].w * qscale) & 255;
    qr[idx4] = b0 | (b1 << 8) | (b2 << 16) | (b3 << 24);
  }
}

// --- Kernel 3: int8 GEMM, 256x256 tile, BK=64, 8 waves (2Mx4N), 4-deep
//     LDS pipeline with counted vmcnt (T3+T4), setprio around MFMA (T5).
//
// Pipeline invariants (derived, race-free by construction):
//  * 4 LDS buffers, buffer b holds K-tile k with k&3 == b.
//  * While computing K-tile k: phase 1 stages A of k+3, phase 2 stages B of
//    k+3. Target buf (k+3)&3 == (k-1)&3, whose last ds_read completed before
//    tile k began (tile k-1 closing barrier) -> no overwrite race.
//  * Tile-k closing: s_waitcnt vmcnt(8) (outstanding = A,B of k+1..k+3 = 12
//    loads; drains k+1's 4, issued ~2 tiles earlier) then s_barrier (turns
//    per-wave residency into whole-tile residency). Tail: 8 -> 4 -> 0.
//  * asm volatile + "memory" on every vmcnt pins staging/ds_read motion at
//    tile boundaries; ds_read->MFMA ordering is compiler-tracked (C loads).
//
// LDS swizzle (BK=64 => 4x16B chunks/row): phys chunk = (logical + row/2)&3.
// Read (16 consecutive rows, fixed logical chunk q) hits slot positions
// {0,4,1,5,2,6,3,7} over 8 rows = exact 2-way bank aliasing = free (m136).
// Staging inverts it on the global source column; LDS dest stays linear.
#define BT 256   // tile M = tile N
#define BK 64

__global__ __launch_bounds__(512, 2) void gemm_i8_kernel(
    const int8_t* __restrict__ xq, const int8_t* __restrict__ wq,
    const float* __restrict__ inv_scale, const float* __restrict__ bias,
    float* __restrict__ out) {
  __shared__ __align__(16) int8_t As[4][BT * BK];   // 4 x 16 KB
  __shared__ __align__(16) int8_t Bs[4][BT * BK];   // 4 x 16 KB  (128 KB total)

  const int t = threadIdx.x;
  const int wave = t >> 6, lane = t & 63;
  const int m0 = blockIdx.y * BT, n0 = blockIdx.x * BT;
  const int wm = wave >> 2;          // 0..1 : 128-row band
  const int wn = wave & 3;           // 0..3 : 64-col band
  const int fr = lane & 15, q = lane >> 4;

  // staging: thread t covers phys 16B chunks p = t and p = 512+t of each 16KB tile
  int srow[2], scol[2];
#pragma unroll
  for (int i = 0; i < 2; ++i) {
    const int p = i * 512 + t;
    srow[i] = p >> 2;
    scol[i] = (((p & 3) - (srow[i] >> 1)) & 3) * 16;   // inverse swizzle on source
  }

  const int8_t* Ag = xq + (size_t)m0 * DIN;
  const int8_t* Bg = wq + (size_t)n0 * DIN;

  // fragment read offsets (swizzled); swz depends on lane only
  const int swz = ((q + (fr >> 1)) & 3) * 16;
  int offA[8], offB[4];
#pragma unroll
  for (int mi = 0; mi < 8; ++mi) offA[mi] = (wm * 128 + mi * 16 + fr) * BK + swz;
#pragma unroll
  for (int ni = 0; ni < 4; ++ni) offB[ni] = (wn * 64 + ni * 16 + fr) * BK + swz;

  v4i acc[8][4];
#pragma unroll
  for (int mi = 0; mi < 8; ++mi)
#pragma unroll
    for (int ni = 0; ni < 4; ++ni) acc[mi][ni] = (v4i){0, 0, 0, 0};

#define STAGE_A(buf, kt)                                                        \
  do {                                                                          \
    async16(Ag + (size_t)srow[0] * DIN + (kt) * BK + scol[0], &As[buf][t * 16]);\
    async16(Ag + (size_t)srow[1] * DIN + (kt) * BK + scol[1],                   \
            &As[buf][8192 + t * 16]);                                           \
  } while (0)
#define STAGE_B(buf, kt)                                                        \
  do {                                                                          \
    async16(Bg + (size_t)srow[0] * DIN + (kt) * BK + scol[0], &Bs[buf][t * 16]);\
    async16(Bg + (size_t)srow[1] * DIN + (kt) * BK + scol[1],                   \
            &Bs[buf][8192 + t * 16]);                                           \
  } while (0)

#define VMCNT8 asm volatile("s_waitcnt vmcnt(8)" ::: "memory")
#define VMCNT4 asm volatile("s_waitcnt vmcnt(4)" ::: "memory")
#define VMCNT0 asm volatile("s_waitcnt vmcnt(0)" ::: "memory")

  // One K-tile: 2 phases of 16 MFMA (mi-half quadrants); B frags reused.
#define KTILE(bufidx, DO_STAGE, kt, WAITSTMT)                                   \
  do {                                                                          \
    const int8_t* Ab = &As[bufidx][0];                                          \
    const int8_t* Bb = &Bs[bufidx][0];                                          \
    v4i a[4], b[4];                                                             \
    _Pragma("unroll") for (int j = 0; j < 4; ++j)                               \
        b[j] = *(const v4i*)(Bb + offB[j]);                                     \
    _Pragma("unroll") for (int j = 0; j < 4; ++j)                               \
        a[j] = *(const v4i*)(Ab + offA[j]);                                     \
    if (DO_STAGE) STAGE_A(((kt) + 3) & 3, (kt) + 3);                            \
    __builtin_amdgcn_s_barrier();                                               \
    __builtin_amdgcn_s_setprio(1);                                              \
    _Pragma("unroll") for (int mi = 0; mi < 4; ++mi)                            \
        _Pragma("unroll") for (int ni = 0; ni < 4; ++ni)                        \
            acc[mi][ni] = __builtin_amdgcn_mfma_i32_16x16x64_i8(                \
                a[mi], b[ni], acc[mi][ni], 0, 0, 0);                            \
    __builtin_amdgcn_s_setprio(0);                                              \
    __builtin_amdgcn_s_barrier();                                               \
    _Pragma("unroll") for (int j = 0; j < 4; ++j)                               \
        a[j] = *(const v4i*)(Ab + offA[4 + j]);                                 \
    if (DO_STAGE) STAGE_B(((kt) + 3) & 3, (kt) + 3);                            \
    __builtin_amdgcn_s_barrier();                                               \
    __builtin_amdgcn_s_setprio(1);                                              \
    _Pragma("unroll") for (int mi = 0; mi < 4; ++mi)                            \
        _Pragma("unroll") for (int ni = 0; ni < 4; ++ni)                        \
            acc[4 + mi][ni] = __builtin_amdgcn_mfma_i32_16x16x64_i8(            \
                a[mi], b[ni], acc[4 + mi][ni], 0, 0, 0);                        \
    __builtin_amdgcn_s_setprio(0);                                              \
    WAITSTMT;                                                                   \
    __builtin_amdgcn_s_barrier();                                               \
  } while (0)

  // prologue: stage K-tiles 0,1,2 (A,B interleaved so oldest 4 loads = tile 0)
  STAGE_A(0, 0); STAGE_B(0, 0);
  STAGE_A(1, 1); STAGE_B(1, 1);
  STAGE_A(2, 2); STAGE_B(2, 2);
  VMCNT8;                                // 12 outstanding -> tile 0 resident
  __builtin_amdgcn_s_barrier();

  const int NT = DIN / BK;               // 64
#pragma unroll 1
  for (int kt = 0; kt < NT - 3; ++kt)    // kt = 0..60, stages kt+3 <= 63
    KTILE(kt & 3, true, kt, VMCNT8);
  KTILE(1, false, 0, VMCNT4);            // kt = 61 (61&3==1); tile 62 resident
  KTILE(2, false, 0, VMCNT0);            // kt = 62; tile 63 resident
  KTILE(3, false, 0, (void)0);           // kt = 63

  // epilogue: C/D layout col = lane&15, row = (lane>>4)*4 + reg (verified)
  const int col = lane & 15;
  const int rb = (lane >> 4) * 4;
#pragma unroll
  for (int mi = 0; mi < 8; ++mi) {
    float sc[4];
#pragma unroll
    for (int r = 0; r < 4; ++r) sc[r] = inv_scale[m0 + wm * 128 + mi * 16 + rb + r];
#pragma unroll
    for (int ni = 0; ni < 4; ++ni) {
      const int gc = n0 + wn * 64 + ni * 16 + col;
      const float bb = bias[gc];
#pragma unroll
      for (int r = 0; r < 4; ++r) {
        const int gr = m0 + wm * 128 + mi * 16 + rb + r;
        out[(size_t)gr * DOUT + gc] = (float)acc[mi][ni][r] * sc[r] + bb;
      }
    }
  }
}

extern "C" void kernel_launch(void* const* d_in, const int* in_sizes, int n_in,
                              void* d_out, int out_size, void* d_ws, size_t ws_size,
                              hipStream_t stream) {
  const float* x       = (const float*)d_in[0];
  const float* w       = (const float*)d_in[1];
  const float* scale_w = (const float*)d_in[2];
  const float* gamma   = (const float*)d_in[3];
  const float* bias    = (const float*)d_in[4];
  float* out = (float*)d_out;
  const int M = in_sizes[0] / DIN;   // 16384

  // workspace layout: wq (16 MB) | xq (64 MB) | inv_scale (64 KB)
  int8_t* wq = (int8_t*)d_ws;
  int8_t* xq = wq + (size_t)DOUT * DIN;
  float* inv_scale = (float*)(xq + (size_t)M * DIN);

  hipLaunchKernelGGL(wconvert_kernel, dim3((DOUT * DIN) / (256 * 4)), dim3(256), 0, stream,
                     w, wq);
  hipLaunchKernelGGL(rmsnorm_quant_kernel, dim3(M), dim3(256), 0, stream,
                     x, gamma, scale_w, xq, inv_scale);
  hipLaunchKernelGGL(gemm_i8_kernel, dim3(DOUT / BT, M / BT), dim3(512), 0, stream,
                     xq, wq, inv_scale, bias, out);
}

// Round 3
// 783.869 us; speedup vs baseline: 1.1405x; 1.0061x over previous
//
#include <hip/hip_runtime.h>
#include <cstdint>

#define DIN 4096
#define DOUT 4096
#define QMAXF 127.0f

typedef int v4i __attribute__((ext_vector_type(4)));
typedef unsigned int u32;

__device__ __forceinline__ void async16(const void* g, void* l) {
  __builtin_amdgcn_global_load_lds((const __attribute__((address_space(1))) u32*)g,
                                   (__attribute__((address_space(3))) u32*)l,
                                   16, 0, 0);
}

__device__ __forceinline__ int clamp_q(float v) {
  int i = (int)rintf(v);           // v_rndne: round half to even, matches np.round
  return i < -128 ? -128 : (i > 127 ? 127 : i);
}

// --- Kernel 1: ternary f32 weights -> int8 (w values are exactly -1/0/1) ---
__global__ __launch_bounds__(256) void wconvert_kernel(const float* __restrict__ w,
                                                       int8_t* __restrict__ wq) {
  int t = blockIdx.x * 256 + threadIdx.x;
  float4 v = ((const float4*)w)[t];
  int b0 = ((int)v.x) & 255, b1 = ((int)v.y) & 255;
  int b2 = ((int)v.z) & 255, b3 = ((int)v.w) & 255;
  ((int*)wq)[t] = b0 | (b1 << 8) | (b2 << 16) | (b3 << 24);
}

// --- Kernel 2: RMSNorm + per-token absmax int8 quant ---
// Grid-stride at 2048 blocks (G11): 8 tokens/block, gamma held in registers
// across tokens. __syncthreads at loop end protects s_ss/s_am reuse.
__global__ __launch_bounds__(256) void rmsnorm_quant_kernel(
    const float* __restrict__ x, const float* __restrict__ gamma,
    const float* __restrict__ scale_w_ptr, int8_t* __restrict__ xq,
    float* __restrict__ inv_scale, int M) {
  const int t = threadIdx.x;
  const int wave = t >> 6, lane = t & 63;
  __shared__ float s_ss[4], s_am[4];

  float4 gv[4];
#pragma unroll
  for (int i = 0; i < 4; ++i) gv[i] = *(const float4*)(gamma + (i * 256 + t) * 4);
  const float sw = scale_w_ptr[0];

  for (int token = blockIdx.x; token < M; token += gridDim.x) {
    const float* xr = x + (size_t)token * DIN;
    float4 xv[4];
    float ss = 0.f, amax = 0.f;
#pragma unroll
    for (int i = 0; i < 4; ++i) {
      xv[i] = *(const float4*)(xr + (i * 256 + t) * 4);
      ss += xv[i].x * xv[i].x + xv[i].y * xv[i].y + xv[i].z * xv[i].z + xv[i].w * xv[i].w;
      amax = fmaxf(amax, fabsf(xv[i].x * gv[i].x));
      amax = fmaxf(amax, fabsf(xv[i].y * gv[i].y));
      amax = fmaxf(amax, fabsf(xv[i].z * gv[i].z));
      amax = fmaxf(amax, fabsf(xv[i].w * gv[i].w));
    }
#pragma unroll
    for (int o = 32; o > 0; o >>= 1) {
      ss += __shfl_down(ss, o);
      amax = fmaxf(amax, __shfl_down(amax, o));
    }
    if (lane == 0) { s_ss[wave] = ss; s_am[wave] = amax; }
    __syncthreads();
    const float tot = s_ss[0] + s_ss[1] + s_ss[2] + s_ss[3];
    const float mx = fmaxf(fmaxf(s_am[0], s_am[1]), fmaxf(s_am[2], s_am[3]));
    const float rstd = rsqrtf(tot * (1.0f / DIN) + 1e-5f);
    const float absmax = fmaxf(mx * rstd, 1e-5f);
    const float qscale = rstd * (QMAXF / absmax);
    if (t == 0) inv_scale[token] = absmax / (QMAXF * sw);

    int* qr = (int*)(xq + (size_t)token * DIN);
#pragma unroll
    for (int i = 0; i < 4; ++i) {
      int b0 = clamp_q(xv[i].x * gv[i].x * qscale) & 255;
      int b1 = clamp_q(xv[i].y * gv[i].y * qscale) & 255;
      int b2 = clamp_q(xv[i].z * gv[i].z * qscale) & 255;
      int b3 = clamp_q(xv[i].w * gv[i].w * qscale) & 255;
      qr[i * 256 + t] = b0 | (b1 << 8) | (b2 << 16) | (b3 << 24);
    }
    __syncthreads();   // s_ss/s_am reused next token
  }
}

// --- Kernel 3: int8 GEMM, 256x256 tile, BK=64, 8 waves (2Mx4N).
//     Register-double-buffered pipeline (AITER shape): per K-tile one
//     barrier, one counted vmcnt, 32 MFMA; ds_reads of tile k+1's fragments
//     and global_load_lds of tile k+3 issue BEFORE the MFMA cluster so the
//     LDS unit and VMEM fly under the matrix pipe.
//
// Invariants (race-free by construction):
//  * 4 LDS buffers; buffer b holds K-tile k with k&3 == b. 16KB A + 16KB B
//    each -> 128 KB, 1 block/CU, 2 waves/SIMD.
//  * At the opening barrier of tile k: tile k AND k+1 are LDS-resident,
//    registers cur = frags(k) (read during tile k-1).
//  * During tile k: stage tile k+3 into buf (k-1)&3 (its last ds_read was
//    during tile k-2, two barriers ago); ds_read frags(k+1) into nxt;
//    MFMA on cur (lgkm: compiler waits only for cur's 12 reads, leaving
//    nxt's 12 in flight).
//  * Close of tile k: vmcnt(4) (outstanding = t(k+2) 4 + t(k+3) 4; drains
//    t(k+2), issued one full tile earlier) then s_barrier -> whole-tile
//    residency of k+2 at open of k+1. Tail: 4 -> 0 -> fence.
//
// LDS swizzle (BK=64 => 4x16B chunks/row): phys chunk = (logical + row/2)&3;
// reads are exact 2-way bank aliasing = free (m136); staging inverts the
// swizzle on the global source column; LDS dest stays linear. Identical
// bytes to the round-2 kernel (3x harness-verified, absmax 0.015625).
#define BT 256   // tile M = tile N
#define BK 64

__global__ __launch_bounds__(512, 2) void gemm_i8_kernel(
    const int8_t* __restrict__ xq, const int8_t* __restrict__ wq,
    const float* __restrict__ inv_scale, const float* __restrict__ bias,
    float* __restrict__ out) {
  __shared__ __align__(16) int8_t As[4][BT * BK];   // 4 x 16 KB
  __shared__ __align__(16) int8_t Bs[4][BT * BK];   // 4 x 16 KB  (128 KB total)

  const int t = threadIdx.x;
  const int wave = t >> 6, lane = t & 63;
  const int m0 = blockIdx.y * BT, n0 = blockIdx.x * BT;
  const int wm = wave >> 2;          // 0..1 : 128-row band
  const int wn = wave & 3;           // 0..3 : 64-col band
  const int fr = lane & 15, q = lane >> 4;

  // staging: thread t covers phys 16B chunks p = t and p = 512+t of each 16KB tile
  int srow[2], scol[2];
#pragma unroll
  for (int i = 0; i < 2; ++i) {
    const int p = i * 512 + t;
    srow[i] = p >> 2;
    scol[i] = (((p & 3) - (srow[i] >> 1)) & 3) * 16;   // inverse swizzle on source
  }

  const int8_t* Ag = xq + (size_t)m0 * DIN;
  const int8_t* Bg = wq + (size_t)n0 * DIN;

  // fragment read offsets (swizzled); swz depends on lane only
  const int swz = ((q + (fr >> 1)) & 3) * 16;
  int offA[8], offB[4];
#pragma unroll
  for (int mi = 0; mi < 8; ++mi) offA[mi] = (wm * 128 + mi * 16 + fr) * BK + swz;
#pragma unroll
  for (int ni = 0; ni < 4; ++ni) offB[ni] = (wn * 64 + ni * 16 + fr) * BK + swz;

  v4i acc[8][4];
#pragma unroll
  for (int mi = 0; mi < 8; ++mi)
#pragma unroll
    for (int ni = 0; ni < 4; ++ni) acc[mi][ni] = (v4i){0, 0, 0, 0};

#define STAGE_AB(buf, kt)                                                       \
  do {                                                                          \
    async16(Ag + (size_t)srow[0] * DIN + (kt) * BK + scol[0], &As[buf][t * 16]);\
    async16(Ag + (size_t)srow[1] * DIN + (kt) * BK + scol[1],                   \
            &As[buf][8192 + t * 16]);                                           \
    async16(Bg + (size_t)srow[0] * DIN + (kt) * BK + scol[0], &Bs[buf][t * 16]);\
    async16(Bg + (size_t)srow[1] * DIN + (kt) * BK + scol[1],                   \
            &Bs[buf][8192 + t * 16]);                                           \
  } while (0)

#define READF(A_, B_, bufi)                                                     \
  do {                                                                          \
    const int8_t* Ab_ = &As[bufi][0];                                           \
    const int8_t* Bb_ = &Bs[bufi][0];                                           \
    _Pragma("unroll") for (int j = 0; j < 4; ++j)                               \
        B_[j] = *(const v4i*)(Bb_ + offB[j]);                                   \
    _Pragma("unroll") for (int j = 0; j < 8; ++j)                               \
        A_[j] = *(const v4i*)(Ab_ + offA[j]);                                   \
  } while (0)

#define MMA(A_, B_)                                                             \
  do {                                                                          \
    __builtin_amdgcn_s_setprio(1);                                              \
    _Pragma("unroll") for (int mi = 0; mi < 8; ++mi)                            \
        _Pragma("unroll") for (int ni = 0; ni < 4; ++ni)                        \
            acc[mi][ni] = __builtin_amdgcn_mfma_i32_16x16x64_i8(                \
                A_[mi], B_[ni], acc[mi][ni], 0, 0, 0);                          \
    __builtin_amdgcn_s_setprio(0);                                              \
  } while (0)

#define VMCNT4 asm volatile("s_waitcnt vmcnt(4)" ::: "memory")
#define VMCNT0 asm volatile("s_waitcnt vmcnt(0)" ::: "memory")
#define MEMFENCE asm volatile("" ::: "memory")

  // Tile k: stage k+3 (optional), prefetch frags(k+1) into NXT, MFMA on CUR.
#define KT(CA, CB, NA, NB, kt, DO_STAGE, WAIT)                                  \
  do {                                                                          \
    if (DO_STAGE) STAGE_AB(((kt) + 3) & 3, (kt) + 3);                           \
    READF(NA, NB, ((kt) + 1) & 3);                                              \
    MMA(CA, CB);                                                                \
    WAIT;                                                                       \
    __builtin_amdgcn_s_barrier();                                               \
  } while (0)

  // prologue: stage tiles 0,1,2; make 0 AND 1 resident; preload frags(0)
  STAGE_AB(0, 0);
  STAGE_AB(1, 1);
  STAGE_AB(2, 2);
  VMCNT4;                                // 12 outstanding -> drains t0,t1
  __builtin_amdgcn_s_barrier();

  v4i a0[8], b0[4], a1[8], b1[4];
  READF(a0, b0, 0);

  const int NT = DIN / BK;               // 64
#pragma unroll 1
  for (int kt = 0; kt < NT - 4; kt += 2) {   // tiles 0..59, stages 3..62
    KT(a0, b0, a1, b1, kt,     true, VMCNT4);
    KT(a1, b1, a0, b0, kt + 1, true, VMCNT4);
  }
  KT(a0, b0, a1, b1, 60, true,  VMCNT4);   // stages t63; nxt = frags(61)
  KT(a1, b1, a0, b0, 61, false, VMCNT0);   // nxt = frags(62); drain t63
  KT(a0, b0, a1, b1, 62, false, MEMFENCE); // nxt = frags(63)
  MMA(a1, b1);                             // tile 63

  // epilogue: C/D layout col = lane&15, row = (lane>>4)*4 + reg (verified)
  const int col = lane & 15;
  const int rb = (lane >> 4) * 4;
#pragma unroll
  for (int mi = 0; mi < 8; ++mi) {
    float sc[4];
#pragma unroll
    for (int r = 0; r < 4; ++r) sc[r] = inv_scale[m0 + wm * 128 + mi * 16 + rb + r];
#pragma unroll
    for (int ni = 0; ni < 4; ++ni) {
      const int gc = n0 + wn * 64 + ni * 16 + col;
      const float bb = bias[gc];
#pragma unroll
      for (int r = 0; r < 4; ++r) {
        const int gr = m0 + wm * 128 + mi * 16 + rb + r;
        out[(size_t)gr * DOUT + gc] = (float)acc[mi][ni][r] * sc[r] + bb;
      }
    }
  }
}

extern "C" void kernel_launch(void* const* d_in, const int* in_sizes, int n_in,
                              void* d_out, int out_size, void* d_ws, size_t ws_size,
                              hipStream_t stream) {
  const float* x       = (const float*)d_in[0];
  const float* w       = (const float*)d_in[1];
  const float* scale_w = (const float*)d_in[2];
  const float* gamma   = (const float*)d_in[3];
  const float* bias    = (const float*)d_in[4];
  float* out = (float*)d_out;
  const int M = in_sizes[0] / DIN;   // 16384

  // workspace layout: wq (16 MB) | xq (64 MB) | inv_scale (64 KB)
  int8_t* wq = (int8_t*)d_ws;
  int8_t* xq = wq + (size_t)DOUT * DIN;
  float* inv_scale = (float*)(xq + (size_t)M * DIN);

  hipLaunchKernelGGL(wconvert_kernel, dim3((DOUT * DIN) / (256 * 4)), dim3(256), 0, stream,
                     w, wq);
  hipLaunchKernelGGL(rmsnorm_quant_kernel, dim3(2048), dim3(256), 0, stream,
                     x, gamma, scale_w, xq, inv_scale, M);
  hipLaunchKernelGGL(gemm_i8_kernel, dim3(DOUT / BT, M / BT), dim3(512), 0, stream,
                     xq, wq, inv_scale, bias, out);
}